// Round 2
// baseline (1083.791 us; speedup 1.0000x reference)
//
#include <hip/hip_runtime.h>
#include <hip/hip_bf16.h>

#define B_ 8
#define N_ 256
#define IN_ 256
#define OUT_ 256
#define H_ 4
#define HD_ 64
#define ALPHA_ 0.2f
#define EPS_ 1e-5f

// ws layout (fp32): Wh | ei | ej | si | sj  each [B][H][N][HD], then concat [B][N][H*HD]
#define S_ (B_*H_*N_*HD_)   // 524288 floats per array; total ws = 6*S_*4 = ~12.6 MB

__device__ __forceinline__ float lrelu(float x) { return x > 0.f ? x : ALPHA_ * x; }

// ---------------------------------------------------------------------------
// Kernel 1: per (b,head,n): Wh = h@W ; ei = h@We1[:IN]+be1 ; ej = h@We1[IN:]
//           then si = Wh@Wa + ba1 ; sj = Wh@Wb
// 192 threads: 3 waves -> (a,d) = (array, col) for phase 2; 128 used in phase 3.
// ---------------------------------------------------------------------------
__global__ __launch_bounds__(192) void prep_kernel(
    const float* __restrict__ h, const float* __restrict__ W,
    const float* __restrict__ We1, const float* __restrict__ be1,
    const float* __restrict__ Wa1, const float* __restrict__ ba1,
    float* __restrict__ ws)
{
    const int idx  = blockIdx.x;
    const int n    = idx & (N_ - 1);
    const int head = (idx >> 8) & (H_ - 1);
    const int b    = idx >> 10;
    const int tid  = threadIdx.x;

    __shared__ float hrow[IN_];
    __shared__ float whrow[HD_];

    const float* hp = h + (size_t)(b * N_ + n) * IN_;
    for (int f = tid; f < IN_; f += 192) hrow[f] = hp[f];
    __syncthreads();

    float* Wh = ws;
    float* ei = ws + S_;
    float* ej = ws + 2 * S_;
    float* si = ws + 3 * S_;
    float* sj = ws + 4 * S_;
    const int rowoff = ((b * H_ + head) * N_ + n) * HD_;

    const int a = tid >> 6;
    const int d = tid & 63;
    const float* wp;
    if (a == 0)      wp = W   + (size_t)(head * IN_) * HD_ + d;
    else if (a == 1) wp = We1 + (size_t)(head * 2 * IN_) * HD_ + d;
    else             wp = We1 + (size_t)(head * 2 * IN_ + IN_) * HD_ + d;

    float acc = 0.f;
    #pragma unroll 4
    for (int f = 0; f < IN_; ++f) acc += hrow[f] * wp[(size_t)f * HD_];

    if (a == 0)      { Wh[rowoff + d] = acc; whrow[d] = acc; }
    else if (a == 1) { ei[rowoff + d] = acc + be1[head * HD_ + d]; }
    else             { ej[rowoff + d] = acc; }
    __syncthreads();

    if (tid < 128) {
        const int a2 = tid >> 6;   // 0 -> si (Wa rows 0..63), 1 -> sj (Wb rows 64..127)
        const int e  = tid & 63;
        const float* wap = Wa1 + (size_t)(head * 3 * HD_ + a2 * HD_) * HD_ + e;
        float acc2 = 0.f;
        #pragma unroll 4
        for (int dd = 0; dd < HD_; ++dd) acc2 += whrow[dd] * wap[(size_t)dd * HD_];
        if (a2 == 0) si[rowoff + e] = acc2 + ba1[head * HD_ + e];
        else         sj[rowoff + e] = acc2;
    }
}

// ---------------------------------------------------------------------------
// Kernel 2: one block per (b,head,i). Thread j in [0,256):
//   t = lrelu(ei_i + ej_j); u = t @ We; logit = sum_e lrelu(si+sj+u)*wa2 + ba2
//   mask, block softmax over j, hp_i = attn @ Wh, per-head layernorm -> concat
// ---------------------------------------------------------------------------
__global__ __launch_bounds__(256, 2) void attn_kernel(
    const int* __restrict__ adj, const float* __restrict__ Wa1,
    const float* __restrict__ wa2, const float* __restrict__ ba2,
    const float* __restrict__ ln_g, const float* __restrict__ ln_b,
    float* __restrict__ ws)
{
    const int idx  = blockIdx.x;
    const int i    = idx & (N_ - 1);
    const int head = (idx >> 8) & (H_ - 1);
    const int b    = idx >> 10;
    const int tid  = threadIdx.x;
    const int lane = tid & 63;
    const int wid  = tid >> 6;

    __shared__ float We_s[HD_ * HD_];      // 16 KB, [d][e]
    __shared__ float ei_s[HD_], si_s[HD_], wa2_s[HD_];
    __shared__ float attn_s[N_];
    __shared__ float hp_s[N_];
    __shared__ float red_s[8];

    const float* Wh = ws;
    const float* ei = ws + S_;
    const float* ej = ws + 2 * S_;
    const float* si = ws + 3 * S_;
    const float* sj = ws + 4 * S_;
    float* concat   = ws + 5 * S_;

    const int bh = b * H_ + head;

    const float* wep = Wa1 + (size_t)(head * 3 * HD_ + 2 * HD_) * HD_;  // We rows 128..191
    for (int k = tid; k < HD_ * HD_; k += 256) We_s[k] = wep[k];
    if (tid < HD_) {
        ei_s[tid]  = ei[(size_t)(bh * N_ + i) * HD_ + tid];
        si_s[tid]  = si[(size_t)(bh * N_ + i) * HD_ + tid];
        wa2_s[tid] = wa2[head * HD_ + tid];
    }
    __syncthreads();

    const int j = tid;
    float t[HD_];
    {
        const float4* ejr = (const float4*)(ej + (size_t)(bh * N_ + j) * HD_);
        #pragma unroll
        for (int d4 = 0; d4 < HD_ / 4; ++d4) {
            float4 v = ejr[d4];
            t[d4 * 4 + 0] = lrelu(ei_s[d4 * 4 + 0] + v.x);
            t[d4 * 4 + 1] = lrelu(ei_s[d4 * 4 + 1] + v.y);
            t[d4 * 4 + 2] = lrelu(ei_s[d4 * 4 + 2] + v.z);
            t[d4 * 4 + 3] = lrelu(ei_s[d4 * 4 + 3] + v.w);
        }
    }

    const float4* sjr = (const float4*)(sj + (size_t)(bh * N_ + j) * HD_);
    float logit = 0.f;
    for (int ec = 0; ec < 4; ++ec) {          // 16-wide e-chunks (rolled: keeps I$ small)
        float u[16];
        #pragma unroll
        for (int k = 0; k < 16; ++k) u[k] = 0.f;
        #pragma unroll
        for (int d = 0; d < HD_; ++d) {       // fully unrolled so t[] stays in VGPRs
            const float4* wr = (const float4*)(We_s + d * HD_ + ec * 16);
            const float td = t[d];
            float4 w0 = wr[0], w1 = wr[1], w2 = wr[2], w3 = wr[3];
            u[0]  += td * w0.x; u[1]  += td * w0.y; u[2]  += td * w0.z; u[3]  += td * w0.w;
            u[4]  += td * w1.x; u[5]  += td * w1.y; u[6]  += td * w1.z; u[7]  += td * w1.w;
            u[8]  += td * w2.x; u[9]  += td * w2.y; u[10] += td * w2.z; u[11] += td * w2.w;
            u[12] += td * w3.x; u[13] += td * w3.y; u[14] += td * w3.z; u[15] += td * w3.w;
        }
        #pragma unroll
        for (int k4 = 0; k4 < 4; ++k4) {
            float4 sv = sjr[ec * 4 + k4];
            const int e = ec * 16 + k4 * 4;
            logit += lrelu(si_s[e + 0] + sv.x + u[k4 * 4 + 0]) * wa2_s[e + 0];
            logit += lrelu(si_s[e + 1] + sv.y + u[k4 * 4 + 1]) * wa2_s[e + 1];
            logit += lrelu(si_s[e + 2] + sv.z + u[k4 * 4 + 2]) * wa2_s[e + 2];
            logit += lrelu(si_s[e + 3] + sv.w + u[k4 * 4 + 3]) * wa2_s[e + 3];
        }
    }
    logit += ba2[head];
    if (adj[(size_t)(b * N_ + i) * N_ + j] == 0) logit = -1e9f;

    // ---- block softmax over j (256 threads) ----
    float m = logit;
    #pragma unroll
    for (int off = 32; off >= 1; off >>= 1) m = fmaxf(m, __shfl_xor(m, off, 64));
    if (lane == 0) red_s[wid] = m;
    __syncthreads();
    m = fmaxf(fmaxf(red_s[0], red_s[1]), fmaxf(red_s[2], red_s[3]));
    const float p = expf(logit - m);
    float ssum = p;
    #pragma unroll
    for (int off = 32; off >= 1; off >>= 1) ssum += __shfl_xor(ssum, off, 64);
    if (lane == 0) red_s[4 + wid] = ssum;
    attn_s[j] = p;
    __syncthreads();
    const float inv = 1.f / (red_s[4] + red_s[5] + red_s[6] + red_s[7]);

    // ---- hp_i[d] = sum_j attn_j * Wh[j][d] : thread = (jg=wid, d=lane) ----
    {
        const float* whp = Wh + (size_t)(bh * N_ + wid * 64) * HD_ + lane;
        float acc = 0.f;
        #pragma unroll 8
        for (int jj = 0; jj < 64; ++jj)
            acc += attn_s[wid * 64 + jj] * whp[(size_t)jj * HD_];
        hp_s[tid] = acc * inv;
    }
    __syncthreads();

    if (tid < 64) {
        const int d = tid;
        const float hp = hp_s[d] + hp_s[64 + d] + hp_s[128 + d] + hp_s[192 + d];
        float s1 = hp;
        #pragma unroll
        for (int off = 32; off >= 1; off >>= 1) s1 += __shfl_xor(s1, off, 64);
        const float mean = s1 * (1.f / 64.f);
        const float df = hp - mean;
        float s2 = df * df;
        #pragma unroll
        for (int off = 32; off >= 1; off >>= 1) s2 += __shfl_xor(s2, off, 64);
        const float var = s2 * (1.f / 64.f);
        const float o = df / sqrtf(var + EPS_) * ln_g[head * HD_ + d] + ln_b[head * HD_ + d];
        concat[(size_t)(b * N_ + i) * OUT_ + head * HD_ + d] = o;
    }
}

// ---------------------------------------------------------------------------
// Kernel 3: out = LN2(concat @ Wo + bo + h). One block per (b,n), thread = o.
// ---------------------------------------------------------------------------
__global__ __launch_bounds__(256) void out_kernel(
    const float* __restrict__ h, const float* __restrict__ Wo,
    const float* __restrict__ bo, const float* __restrict__ ln2_g,
    const float* __restrict__ ln2_b, const float* __restrict__ concat,
    float* __restrict__ out)
{
    const int row  = blockIdx.x;      // b*N + n
    const int tid  = threadIdx.x;
    const int lane = tid & 63;
    const int wid  = tid >> 6;

    __shared__ float crow[OUT_];
    __shared__ float red_s[8];

    crow[tid] = concat[(size_t)row * OUT_ + tid];
    __syncthreads();

    float acc = 0.f;
    const float* wop = Wo + tid;
    #pragma unroll 4
    for (int f = 0; f < OUT_; ++f) acc += crow[f] * wop[(size_t)f * OUT_];
    acc += bo[tid] + h[(size_t)row * OUT_ + tid];

    float s1 = acc;
    #pragma unroll
    for (int off = 32; off >= 1; off >>= 1) s1 += __shfl_xor(s1, off, 64);
    if (lane == 0) red_s[wid] = s1;
    __syncthreads();
    const float mean = (red_s[0] + red_s[1] + red_s[2] + red_s[3]) * (1.f / 256.f);
    const float df = acc - mean;
    float s2 = df * df;
    #pragma unroll
    for (int off = 32; off >= 1; off >>= 1) s2 += __shfl_xor(s2, off, 64);
    if (lane == 0) red_s[4 + wid] = s2;
    __syncthreads();
    const float var = (red_s[4] + red_s[5] + red_s[6] + red_s[7]) * (1.f / 256.f);

    out[(size_t)row * OUT_ + tid] =
        df / sqrtf(var + EPS_) * ln2_g[tid] + ln2_b[tid];
}

// ---------------------------------------------------------------------------
extern "C" void kernel_launch(void* const* d_in, const int* in_sizes, int n_in,
                              void* d_out, int out_size, void* d_ws, size_t ws_size,
                              hipStream_t stream)
{
    const float* h    = (const float*)d_in[0];
    const int*   adj  = (const int*)  d_in[1];
    const float* W    = (const float*)d_in[2];
    const float* We1  = (const float*)d_in[3];
    const float* be1  = (const float*)d_in[4];
    const float* Wa1  = (const float*)d_in[5];
    const float* ba1  = (const float*)d_in[6];
    const float* wa2  = (const float*)d_in[7];
    const float* ba2  = (const float*)d_in[8];
    const float* ln_g = (const float*)d_in[9];
    const float* ln_b = (const float*)d_in[10];
    const float* Wo   = (const float*)d_in[11];
    const float* bo   = (const float*)d_in[12];
    const float* ln2g = (const float*)d_in[13];
    const float* ln2b = (const float*)d_in[14];

    float* ws  = (float*)d_ws;     // needs 6*S_*4 = ~12.6 MB
    float* out = (float*)d_out;

    prep_kernel<<<B_ * H_ * N_, 192, 0, stream>>>(h, W, We1, be1, Wa1, ba1, ws);
    attn_kernel<<<B_ * H_ * N_, 256, 0, stream>>>(adj, Wa1, wa2, ba2, ln_g, ln_b, ws);
    out_kernel <<<B_ * N_,      256, 0, stream>>>(h, Wo, bo, ln2g, ln2b, ws + 5 * (size_t)S_, out);
}

// Round 3
// 347.045 us; speedup vs baseline: 3.1229x; 3.1229x over previous
//
#include <hip/hip_runtime.h>
#include <hip/hip_bf16.h>

#define B_ 8
#define N_ 256
#define IN_ 256
#define OUT_ 256
#define H_ 4
#define HD_ 64
#define ALPHA_ 0.2f
#define EPS_ 1e-5f

// ws layout (float* base):
//   [0,S_)      ei   f32  [B][H][N][HD]
//   [S_,2S_)    si   f32
//   [2S_,3S_)   concat f32 [B][N][OUT]
//   [3S_,4S_)   ej_b bf16 [B][H][N][HD] then Wh_b bf16 (each S_ ushorts)
//   [4S_,...)   bw_b bf16 [H][64 e][128 k]  (k<64 = We[k][e], k>=64 = Wb[k-64][e])
#define S_ (B_*H_*N_*HD_)   // 524288

typedef unsigned short ushort_t;
typedef __attribute__((ext_vector_type(8))) short short8;
typedef __attribute__((ext_vector_type(4))) float floatx4;

__device__ __forceinline__ float lrelu(float x) { return fmaxf(x, ALPHA_ * x); }
__device__ __forceinline__ float b2f(ushort_t u) { return __uint_as_float(((unsigned)u) << 16); }
__device__ __forceinline__ ushort_t f2b(float x) {   // RNE f32->bf16
    unsigned u = __float_as_uint(x);
    unsigned r = ((u >> 16) & 1u) + 0x7fffu;
    return (ushort_t)((u + r) >> 16);
}

// ---------------------------------------------------------------------------
// Kernel 0: build bw_b[h][e][k] = (k<64 ? We[k][e] : Wb[k-64][e]) as bf16.
// We rows = Wa1[128+k], Wb rows = Wa1[64+(k-64)] = Wa1[k].
// ---------------------------------------------------------------------------
__global__ __launch_bounds__(256) void bwprep_kernel(
    const float* __restrict__ Wa1, ushort_t* __restrict__ bw_b)
{
    const int hh = blockIdx.x;
    for (int idx = threadIdx.x; idx < 64 * 128; idx += 256) {
        const int e = idx >> 7, k = idx & 127;
        const int row = (k < 64) ? (128 + k) : k;
        bw_b[hh * 8192 + idx] = f2b(Wa1[(size_t)hh * 3 * HD_ * HD_ + row * HD_ + e]);
    }
}

// ---------------------------------------------------------------------------
// Kernel 1: per (b,head,n): Wh_b = bf16(h@W); ei = h@We1[:IN]+be1 (f32);
//           ej_b = bf16(h@We1[IN:]); si = Wh@Wa + ba1 (f32).
// ---------------------------------------------------------------------------
__global__ __launch_bounds__(192) void prep_kernel(
    const float* __restrict__ h, const float* __restrict__ W,
    const float* __restrict__ We1, const float* __restrict__ be1,
    const float* __restrict__ Wa1, const float* __restrict__ ba1,
    float* __restrict__ ws)
{
    const int idx  = blockIdx.x;
    const int n    = idx & (N_ - 1);
    const int head = (idx >> 8) & (H_ - 1);
    const int b    = idx >> 10;
    const int tid  = threadIdx.x;

    __shared__ float hrow[IN_];
    __shared__ float whrow[HD_];

    const float* hp = h + (size_t)(b * N_ + n) * IN_;
    for (int f = tid; f < IN_; f += 192) hrow[f] = hp[f];
    __syncthreads();

    float*    ei   = ws;
    float*    si   = ws + S_;
    ushort_t* ej_b = (ushort_t*)(ws + 3 * (size_t)S_);
    ushort_t* Wh_b = ej_b + S_;
    const int rowoff = ((b * H_ + head) * N_ + n) * HD_;

    const int a = tid >> 6;
    const int d = tid & 63;
    const float* wp;
    if (a == 0)      wp = W   + (size_t)(head * IN_) * HD_ + d;
    else if (a == 1) wp = We1 + (size_t)(head * 2 * IN_) * HD_ + d;
    else             wp = We1 + (size_t)(head * 2 * IN_ + IN_) * HD_ + d;

    float acc = 0.f;
    #pragma unroll 4
    for (int f = 0; f < IN_; ++f) acc += hrow[f] * wp[(size_t)f * HD_];

    if (a == 0)      { Wh_b[rowoff + d] = f2b(acc); whrow[d] = acc; }
    else if (a == 1) { ei[rowoff + d] = acc + be1[head * HD_ + d]; }
    else             { ej_b[rowoff + d] = f2b(acc); }
    __syncthreads();

    if (tid < 64) {   // si = whrow @ Wa (rows 0..63) + ba1
        const float* wap = Wa1 + (size_t)(head * 3 * HD_) * HD_ + tid;
        float acc2 = 0.f;
        #pragma unroll 4
        for (int dd = 0; dd < HD_; ++dd) acc2 += whrow[dd] * wap[(size_t)dd * HD_];
        si[rowoff + tid] = acc2 + ba1[head * HD_ + tid];
    }
}

// ---------------------------------------------------------------------------
// Kernel 2: one block per (b,head,i), 4 waves.
//  q[j][e] = si[e] + [t | Wh] @ [We; Wb],  t = lrelu(ei_i + ej)
//  logit[j] = sum_e lrelu(q)*wa2 + ba2 -> mask -> softmax -> hp = attn@Wh -> LN
// MFMA: 16x16x32 bf16, M=256 (j, 64/wave), N=64 (e), K=128.
// ---------------------------------------------------------------------------
__global__ __launch_bounds__(256) void attn_kernel(
    const int* __restrict__ adj, const float* __restrict__ wa2,
    const float* __restrict__ ba2, const float* __restrict__ ln_g,
    const float* __restrict__ ln_b, float* __restrict__ ws)
{
    const int idx  = blockIdx.x;
    const int i    = idx & (N_ - 1);
    const int head = (idx >> 8) & (H_ - 1);
    const int b    = idx >> 10;
    const int tid  = threadIdx.x;
    const int lane = tid & 63;
    const int wid  = tid >> 6;
    const int quad = lane >> 4;
    const int l15  = lane & 15;
    const int bh   = b * H_ + head;

    // LDS: pad t_s rows to 72 bf16 (144B: +4 banks/row -> 2-way, free);
    //      bw_s rows to 136 bf16 (272B: same pattern). 16B alignment kept.
    __shared__ ushort_t t_s[N_ * 72];        // 36864 B
    __shared__ ushort_t bw_s[64 * 136];      // 17408 B
    __shared__ float ei_s[64], si_s[64], wa2_s[64];
    __shared__ float logit_s[N_];            // logits, then unnormalized p
    __shared__ float hp_s[N_];
    __shared__ float red_s[8];

    const float*    ei   = ws;
    const float*    si   = ws + S_;
    float*          conc = ws + 2 * (size_t)S_;
    const ushort_t* ej_b = (const ushort_t*)(ws + 3 * (size_t)S_);
    const ushort_t* Wh_b = ej_b + S_;
    const ushort_t* bw_b = (const ushort_t*)(ws + 4 * (size_t)S_);

    if (tid < 64) {
        ei_s[tid]  = ei[(size_t)(bh * N_ + i) * HD_ + tid];
        si_s[tid]  = si[(size_t)(bh * N_ + i) * HD_ + tid];
        wa2_s[tid] = wa2[head * HD_ + tid];
    }
    // stage [We;Wb]^T : 64 rows x 128 k  (uint4 = 8 bf16)
    for (int v = tid; v < 64 * 16; v += 256) {
        const int r = v >> 4, c = v & 15;
        *(uint4*)&bw_s[r * 136 + c * 8] =
            *(const uint4*)&bw_b[head * 8192 + r * 128 + c * 8];
    }
    // stage t = bf16(lrelu(ei + ej)). thread -> (k-chunk c=tid&7, rows r0=tid>>3)
    {
        const int c = tid & 7, r0 = tid >> 3;
        #pragma unroll
        for (int s = 0; s < 8; ++s) {
            const int j = s * 32 + r0;
            uint4 raw = *(const uint4*)&ej_b[((size_t)(bh * N_ + j)) * HD_ + c * 8];
            const unsigned* rw = (const unsigned*)&raw;
            unsigned outw[4];
            #pragma unroll
            for (int p = 0; p < 4; ++p) {
                float x0 = __uint_as_float((rw[p] & 0xffffu) << 16) + ei_s[c * 8 + p * 2];
                float x1 = __uint_as_float(rw[p] & 0xffff0000u)     + ei_s[c * 8 + p * 2 + 1];
                x0 = lrelu(x0); x1 = lrelu(x1);
                outw[p] = (unsigned)f2b(x0) | ((unsigned)f2b(x1) << 16);
            }
            *(uint4*)&t_s[j * 72 + c * 8] = *(uint4*)outw;
        }
    }
    __syncthreads();

    // ---- MFMA: wave wid handles j in [wid*64, wid*64+64) ----
    floatx4 acc[4][4];
    #pragma unroll
    for (int mt = 0; mt < 4; ++mt)
        #pragma unroll
        for (int nt = 0; nt < 4; ++nt) acc[mt][nt] = (floatx4){0.f, 0.f, 0.f, 0.f};

    #pragma unroll
    for (int ks = 0; ks < 4; ++ks) {
        short8 bfr[4], afr[4];
        #pragma unroll
        for (int nt = 0; nt < 4; ++nt)
            bfr[nt] = *(const short8*)&bw_s[(nt * 16 + l15) * 136 + ks * 32 + quad * 8];
        if (ks < 2) {
            #pragma unroll
            for (int mt = 0; mt < 4; ++mt)
                afr[mt] = *(const short8*)&t_s[(wid * 64 + mt * 16 + l15) * 72 + ks * 32 + quad * 8];
        } else {
            #pragma unroll
            for (int mt = 0; mt < 4; ++mt)
                afr[mt] = *(const short8*)&Wh_b[((size_t)(bh * N_ + wid * 64 + mt * 16 + l15)) * HD_
                                                + (ks - 2) * 32 + quad * 8];
        }
        #pragma unroll
        for (int mt = 0; mt < 4; ++mt)
            #pragma unroll
            for (int nt = 0; nt < 4; ++nt)
                acc[mt][nt] = __builtin_amdgcn_mfma_f32_16x16x32_bf16(
                    afr[mt], bfr[nt], acc[mt][nt], 0, 0, 0);
    }

    // ---- epilogue: logit[j] = sum_e lrelu(si+q)*wa2 + ba2 ----
    const float ba2h = ba2[head];
    #pragma unroll
    for (int mt = 0; mt < 4; ++mt) {
        #pragma unroll
        for (int reg = 0; reg < 4; ++reg) {
            float val = 0.f;
            #pragma unroll
            for (int nt = 0; nt < 4; ++nt) {
                const int e = nt * 16 + l15;
                float q = acc[mt][nt][reg] + si_s[e];
                val += lrelu(q) * wa2_s[e];
            }
            val += __shfl_xor(val, 1, 64);
            val += __shfl_xor(val, 2, 64);
            val += __shfl_xor(val, 4, 64);
            val += __shfl_xor(val, 8, 64);
            if (l15 == 0)
                logit_s[wid * 64 + mt * 16 + quad * 4 + reg] = val + ba2h;
        }
    }
    __syncthreads();

    // ---- mask + block softmax over 256 j ----
    float lg = logit_s[tid];
    if (adj[((size_t)(b * N_ + i)) * N_ + tid] == 0) lg = -1e9f;
    float m = lg;
    #pragma unroll
    for (int off = 32; off >= 1; off >>= 1) m = fmaxf(m, __shfl_xor(m, off, 64));
    if (lane == 0) red_s[wid] = m;
    __syncthreads();
    m = fmaxf(fmaxf(red_s[0], red_s[1]), fmaxf(red_s[2], red_s[3]));
    const float p = __expf(lg - m);
    float ssum = p;
    #pragma unroll
    for (int off = 32; off >= 1; off >>= 1) ssum += __shfl_xor(ssum, off, 64);
    logit_s[tid] = p;                 // own slot; safe without extra sync
    if (lane == 0) red_s[4 + wid] = ssum;
    __syncthreads();
    const float inv = 1.f / (red_s[4] + red_s[5] + red_s[6] + red_s[7]);

    // ---- hp[d] = sum_j attn_j * Wh[j][d], thread = (jg=wid, d=lane) ----
    {
        const ushort_t* whp = &Wh_b[((size_t)(bh * N_ + wid * 64)) * HD_ + lane];
        float a0 = 0.f;
        #pragma unroll 8
        for (int jj = 0; jj < 64; ++jj)
            a0 += logit_s[wid * 64 + jj] * b2f(whp[(size_t)jj * HD_]);
        hp_s[tid] = a0 * inv;
    }
    __syncthreads();

    if (tid < 64) {
        const int d = tid;
        const float hp = hp_s[d] + hp_s[64 + d] + hp_s[128 + d] + hp_s[192 + d];
        float s1 = hp;
        #pragma unroll
        for (int off = 32; off >= 1; off >>= 1) s1 += __shfl_xor(s1, off, 64);
        const float mean = s1 * (1.f / 64.f);
        const float df = hp - mean;
        float s2 = df * df;
        #pragma unroll
        for (int off = 32; off >= 1; off >>= 1) s2 += __shfl_xor(s2, off, 64);
        const float var = s2 * (1.f / 64.f);
        const float o = df * __frsqrt_rn(var + EPS_) * ln_g[head * HD_ + d] + ln_b[head * HD_ + d];
        conc[(size_t)(b * N_ + i) * OUT_ + head * HD_ + d] = o;
    }
}

// ---------------------------------------------------------------------------
// Kernel 3: out = LN2(concat @ Wo + bo + h). One block per (b,n), thread = o.
// ---------------------------------------------------------------------------
__global__ __launch_bounds__(256) void out_kernel(
    const float* __restrict__ h, const float* __restrict__ Wo,
    const float* __restrict__ bo, const float* __restrict__ ln2_g,
    const float* __restrict__ ln2_b, const float* __restrict__ concat,
    float* __restrict__ out)
{
    const int row  = blockIdx.x;
    const int tid  = threadIdx.x;
    const int lane = tid & 63;
    const int wid  = tid >> 6;

    __shared__ float crow[OUT_];
    __shared__ float red_s[8];

    crow[tid] = concat[(size_t)row * OUT_ + tid];
    __syncthreads();

    float acc = 0.f;
    const float* wop = Wo + tid;
    #pragma unroll 4
    for (int f = 0; f < OUT_; ++f) acc += crow[f] * wop[(size_t)f * OUT_];
    acc += bo[tid] + h[(size_t)row * OUT_ + tid];

    float s1 = acc;
    #pragma unroll
    for (int off = 32; off >= 1; off >>= 1) s1 += __shfl_xor(s1, off, 64);
    if (lane == 0) red_s[wid] = s1;
    __syncthreads();
    const float mean = (red_s[0] + red_s[1] + red_s[2] + red_s[3]) * (1.f / 256.f);
    const float df = acc - mean;
    float s2 = df * df;
    #pragma unroll
    for (int off = 32; off >= 1; off >>= 1) s2 += __shfl_xor(s2, off, 64);
    if (lane == 0) red_s[4 + wid] = s2;
    __syncthreads();
    const float var = (red_s[4] + red_s[5] + red_s[6] + red_s[7]) * (1.f / 256.f);

    out[(size_t)row * OUT_ + tid] =
        df * __frsqrt_rn(var + EPS_) * ln2_g[tid] + ln2_b[tid];
}

// ---------------------------------------------------------------------------
extern "C" void kernel_launch(void* const* d_in, const int* in_sizes, int n_in,
                              void* d_out, int out_size, void* d_ws, size_t ws_size,
                              hipStream_t stream)
{
    const float* h    = (const float*)d_in[0];
    const int*   adj  = (const int*)  d_in[1];
    const float* W    = (const float*)d_in[2];
    const float* We1  = (const float*)d_in[3];
    const float* be1  = (const float*)d_in[4];
    const float* Wa1  = (const float*)d_in[5];
    const float* ba1  = (const float*)d_in[6];
    const float* wa2  = (const float*)d_in[7];
    const float* ba2  = (const float*)d_in[8];
    const float* ln_g = (const float*)d_in[9];
    const float* ln_b = (const float*)d_in[10];
    const float* Wo   = (const float*)d_in[11];
    const float* bo   = (const float*)d_in[12];
    const float* ln2g = (const float*)d_in[13];
    const float* ln2b = (const float*)d_in[14];

    float* ws = (float*)d_ws;
    ushort_t* bw_b = (ushort_t*)(ws + 4 * (size_t)S_);
    float* out = (float*)d_out;

    bwprep_kernel<<<H_,          256, 0, stream>>>(Wa1, bw_b);
    prep_kernel <<<B_ * H_ * N_, 192, 0, stream>>>(h, W, We1, be1, Wa1, ba1, ws);
    attn_kernel <<<B_ * H_ * N_, 256, 0, stream>>>(adj, wa2, ba2, ln_g, ln_b, ws);
    out_kernel  <<<B_ * N_,      256, 0, stream>>>(h, Wo, bo, ln2g, ln2b, ws + 2 * (size_t)S_, out);
}

// Round 4
// 293.595 us; speedup vs baseline: 3.6914x; 1.1821x over previous
//
#include <hip/hip_runtime.h>
#include <hip/hip_bf16.h>

#define B_ 8
#define N_ 256
#define IN_ 256
#define OUT_ 256
#define H_ 4
#define HD_ 64
#define ALPHA_ 0.2f
#define EPS_ 1e-5f

#define S_ (B_*H_*N_*HD_)   // 524288

// ws layout (float* base ws):
//   ei_f   f32   [ws + 0,    S_)          [B][H][N][64]  (+be1)
//   si_f   f32   [ws + S_,  2S_)          [B][H][N][64]  (+ba1)
//   ej_b   bf16  at ws+2S_   (S_ ushorts) [B][H][N][64]
//   Wh_b   bf16  ej_b+S_     (S_ ushorts)
//   h_b    bf16  at ws+3S_   (B*N*256 = S_ ushorts... = 524288)
//   conc_b bf16  h_b+524288  (524288)
//   wfull  bf16  at ws+4S_   (1024*256 = 262144)   [4 heads x {Wh|ei|ej|si}][256 f]
//   wo_t   bf16  wfull+262144 (65536)              [o][f]
//   bw_b   bf16  wo_t+65536   (4*64*128 = 32768)   [h][e][k: We|Wb]

typedef unsigned short ushort_t;
typedef __attribute__((ext_vector_type(8))) short short8;
typedef __attribute__((ext_vector_type(4))) float floatx4;

__device__ __forceinline__ float lrelu(float x) { return fmaxf(x, ALPHA_ * x); }
__device__ __forceinline__ float b2f(ushort_t u) { return __uint_as_float(((unsigned)u) << 16); }
__device__ __forceinline__ ushort_t f2b(float x) {   // RNE f32->bf16
    unsigned u = __float_as_uint(x);
    unsigned r = ((u >> 16) & 1u) + 0x7fffu;
    return (ushort_t)((u + r) >> 16);
}

// ---------------------------------------------------------------------------
// h -> bf16 (4 elems/thread, exact grid)
// ---------------------------------------------------------------------------
__global__ __launch_bounds__(256) void conv_h_kernel(
    const float* __restrict__ h, ushort_t* __restrict__ h_b)
{
    const int i = (blockIdx.x * 256 + threadIdx.x) * 4;
    float4 v = *(const float4*)&h[i];
    unsigned w0 = (unsigned)f2b(v.x) | ((unsigned)f2b(v.y) << 16);
    unsigned w1 = (unsigned)f2b(v.z) | ((unsigned)f2b(v.w) << 16);
    uint2 o; o.x = w0; o.y = w1;
    *(uint2*)&h_b[i] = o;
}

// ---------------------------------------------------------------------------
// wfull[h*256+c][f] (bf16): c<64: W[h][f][c]; 64..127: We1[h][f][c-64];
//   128..191: We1[h][256+f][c-128]; 192..255: (W@Wa)[f][c-192]
// grid = H*256 (h, f), 256 threads (c)
// ---------------------------------------------------------------------------
__global__ __launch_bounds__(256) void build_w_kernel(
    const float* __restrict__ W, const float* __restrict__ We1,
    const float* __restrict__ Wa1, ushort_t* __restrict__ wfull)
{
    const int hh = blockIdx.x >> 8, f = blockIdx.x & 255;
    const int c = threadIdx.x;
    __shared__ float Wlds[64];
    if (c < 64) Wlds[c] = W[(size_t)(hh * 256 + f) * 64 + c];
    __syncthreads();
    float v;
    if (c < 64)       v = Wlds[c];
    else if (c < 128) v = We1[(size_t)(hh * 512 + f) * 64 + (c - 64)];
    else if (c < 192) v = We1[(size_t)(hh * 512 + 256 + f) * 64 + (c - 128)];
    else {
        float s = 0.f;
        const float* wa = Wa1 + (size_t)hh * 192 * 64 + (c - 192);
        #pragma unroll 4
        for (int g = 0; g < 64; ++g) s += Wlds[g] * wa[(size_t)g * 64];
        v = s;
    }
    wfull[(size_t)(hh * 256 + c) * 256 + f] = f2b(v);
}

// ---------------------------------------------------------------------------
// wo_t[o][f] = bf16(Wo[f][o]) via LDS 64x64 tiles. grid 16 (4x4), 256 thr.
// ---------------------------------------------------------------------------
__global__ __launch_bounds__(256) void build_wot_kernel(
    const float* __restrict__ Wo, ushort_t* __restrict__ wo_t)
{
    const int to = blockIdx.x & 3, tf = blockIdx.x >> 2;
    const int r0 = threadIdx.x >> 6, cc = threadIdx.x & 63;
    __shared__ float t[64][65];
    for (int rr = r0; rr < 64; rr += 4)
        t[rr][cc] = Wo[(size_t)(tf * 64 + rr) * 256 + to * 64 + cc];
    __syncthreads();
    for (int rr = r0; rr < 64; rr += 4)
        wo_t[(size_t)(to * 64 + rr) * 256 + tf * 64 + cc] = f2b(t[cc][rr]);
}

// ---------------------------------------------------------------------------
// bw_b[h][e][k] = (k<64 ? We[k][e] : Wb[k-64][e]); We=Wa1 rows 128..191, Wb=64..127
// ---------------------------------------------------------------------------
__global__ __launch_bounds__(256) void bwprep_kernel(
    const float* __restrict__ Wa1, ushort_t* __restrict__ bw_b)
{
    const int hh = blockIdx.x;
    for (int idx = threadIdx.x; idx < 64 * 128; idx += 256) {
        const int e = idx >> 7, k = idx & 127;
        const int row = (k < 64) ? (128 + k) : k;
        bw_b[hh * 8192 + idx] = f2b(Wa1[(size_t)hh * 192 * 64 + row * 64 + e]);
    }
}

// ---------------------------------------------------------------------------
// prep2: C[2048 rows][1024 cols] = h_b @ wfull^T(col-major), epilogue scatters
// to Wh_b / ei_f / ej_b / si_f. grid 256: gm=blk&31 (M=64), gn=blk>>5 (N=128).
// 4 waves: wave w covers cols gn*128 + w*32 (+nt*16), nt in {0,1}.
// ---------------------------------------------------------------------------
__global__ __launch_bounds__(256) void prep2_kernel(
    const ushort_t* __restrict__ h_b, const ushort_t* __restrict__ wfull,
    const float* __restrict__ be1, const float* __restrict__ ba1,
    float* __restrict__ ws)
{
    const int gm = blockIdx.x & 31, gn = blockIdx.x >> 5;
    const int tid = threadIdx.x, lane = tid & 63, wid = tid >> 6;
    const int quad = lane >> 4, l15 = lane & 15;

    float*    ei_f = ws;
    float*    si_f = ws + S_;
    ushort_t* ej_b = (ushort_t*)(ws + 2 * (size_t)S_);
    ushort_t* Wh_b = ej_b + S_;

    floatx4 acc[4][2];
    #pragma unroll
    for (int mt = 0; mt < 4; ++mt)
        #pragma unroll
        for (int nt = 0; nt < 2; ++nt) acc[mt][nt] = (floatx4){0.f,0.f,0.f,0.f};

    #pragma unroll 2
    for (int ks = 0; ks < 8; ++ks) {
        short8 afr[4], bfr[2];
        #pragma unroll
        for (int mt = 0; mt < 4; ++mt)
            afr[mt] = *(const short8*)&h_b[(size_t)(gm * 64 + mt * 16 + l15) * 256 + ks * 32 + quad * 8];
        #pragma unroll
        for (int nt = 0; nt < 2; ++nt)
            bfr[nt] = *(const short8*)&wfull[(size_t)(gn * 128 + wid * 32 + nt * 16 + l15) * 256 + ks * 32 + quad * 8];
        #pragma unroll
        for (int mt = 0; mt < 4; ++mt)
            #pragma unroll
            for (int nt = 0; nt < 2; ++nt)
                acc[mt][nt] = __builtin_amdgcn_mfma_f32_16x16x32_bf16(afr[mt], bfr[nt], acc[mt][nt], 0, 0, 0);
    }

    #pragma unroll
    for (int nt = 0; nt < 2; ++nt) {
        const int colg = gn * 128 + wid * 32 + nt * 16 + l15;
        const int head = colg >> 8, c = colg & 255, type = c >> 6, d = c & 63;
        #pragma unroll
        for (int mt = 0; mt < 4; ++mt)
            #pragma unroll
            for (int reg = 0; reg < 4; ++reg) {
                const int row = gm * 64 + mt * 16 + quad * 4 + reg;
                const int b = row >> 8, n = row & 255;
                const size_t idx = ((size_t)(b * H_ + head) * 256 + n) * 64 + d;
                const float v = acc[mt][nt][reg];
                if      (type == 0) Wh_b[idx] = f2b(v);
                else if (type == 1) ei_f[idx] = v + be1[head * 64 + d];
                else if (type == 2) ej_b[idx] = f2b(v);
                else                si_f[idx] = v + ba1[head * 64 + d];
            }
    }
}

// ---------------------------------------------------------------------------
// attn: one block per (b,head,i), 4 waves. K=128 GEMM:
//   k<64:  A = t = lrelu(ei_i + ej_j)  (computed in registers from ej_b)
//   k>=64: A = Wh[j]                    (B half = Wb -> adds sj)
// epilogue: logit = sum_e lrelu(si+acc)*wa2 + ba2 -> mask/softmax -> hp -> LN
// ---------------------------------------------------------------------------
__global__ __launch_bounds__(256) void attn_kernel(
    const int* __restrict__ adj, const float* __restrict__ wa2,
    const float* __restrict__ ba2, const float* __restrict__ ln_g,
    const float* __restrict__ ln_b, float* __restrict__ ws)
{
    const int idx  = blockIdx.x;
    const int i    = idx & (N_ - 1);
    const int head = (idx >> 8) & (H_ - 1);
    const int b    = idx >> 10;
    const int tid  = threadIdx.x;
    const int lane = tid & 63;
    const int wid  = tid >> 6;
    const int quad = lane >> 4;
    const int l15  = lane & 15;
    const int bh   = b * H_ + head;

    __shared__ ushort_t bw_s[64 * 136];                 // 17408 B, row pad 272B
    __shared__ __align__(16) float ei_s[64];
    __shared__ float si_s[64], wa2_s[64];
    __shared__ float logit_s[N_];
    __shared__ float hp_s[N_];
    __shared__ float red_s[8];

    const float*    ei_f = ws;
    const float*    si_f = ws + S_;
    const ushort_t* ej_b = (const ushort_t*)(ws + 2 * (size_t)S_);
    const ushort_t* Wh_b = ej_b + S_;
    ushort_t*       conc = (ushort_t*)(ws + 3 * (size_t)S_) + 524288;
    const ushort_t* bw_b = (const ushort_t*)(ws + 4 * (size_t)S_) + 262144 + 65536;

    if (tid < 64) {
        ei_s[tid]  = ei_f[(size_t)(bh * N_ + i) * HD_ + tid];
        si_s[tid]  = si_f[(size_t)(bh * N_ + i) * HD_ + tid];
        wa2_s[tid] = wa2[head * HD_ + tid];
    }
    for (int v = tid; v < 64 * 16; v += 256) {
        const int r = v >> 4, c = v & 15;
        *(uint4*)&bw_s[r * 136 + c * 8] = *(const uint4*)&bw_b[head * 8192 + r * 128 + c * 8];
    }
    __syncthreads();

    floatx4 acc[4][4];
    #pragma unroll
    for (int mt = 0; mt < 4; ++mt)
        #pragma unroll
        for (int nt = 0; nt < 4; ++nt) acc[mt][nt] = (floatx4){0.f,0.f,0.f,0.f};

    #pragma unroll
    for (int ks = 0; ks < 4; ++ks) {
        short8 bfr[4], afr[4];
        #pragma unroll
        for (int nt = 0; nt < 4; ++nt)
            bfr[nt] = *(const short8*)&bw_s[(nt * 16 + l15) * 136 + ks * 32 + quad * 8];
        if (ks < 2) {
            // t-half: afr computed in registers from ej_b + ei
            float eiv[8];
            *(float4*)&eiv[0] = *(const float4*)&ei_s[ks * 32 + quad * 8];
            *(float4*)&eiv[4] = *(const float4*)&ei_s[ks * 32 + quad * 8 + 4];
            #pragma unroll
            for (int mt = 0; mt < 4; ++mt) {
                uint4 raw = *(const uint4*)&ej_b[((size_t)(bh * N_ + wid * 64 + mt * 16 + l15)) * HD_
                                                 + ks * 32 + quad * 8];
                const unsigned* rw = (const unsigned*)&raw;
                union { unsigned u[4]; short8 s; } ow;
                #pragma unroll
                for (int p = 0; p < 4; ++p) {
                    float x0 = __uint_as_float(rw[p] << 16)          + eiv[2 * p];
                    float x1 = __uint_as_float(rw[p] & 0xffff0000u)  + eiv[2 * p + 1];
                    x0 = lrelu(x0); x1 = lrelu(x1);
                    ow.u[p] = (unsigned)f2b(x0) | ((unsigned)f2b(x1) << 16);
                }
                afr[mt] = ow.s;
            }
        } else {
            #pragma unroll
            for (int mt = 0; mt < 4; ++mt)
                afr[mt] = *(const short8*)&Wh_b[((size_t)(bh * N_ + wid * 64 + mt * 16 + l15)) * HD_
                                                + (ks - 2) * 32 + quad * 8];
        }
        #pragma unroll
        for (int mt = 0; mt < 4; ++mt)
            #pragma unroll
            for (int nt = 0; nt < 4; ++nt)
                acc[mt][nt] = __builtin_amdgcn_mfma_f32_16x16x32_bf16(afr[mt], bfr[nt], acc[mt][nt], 0, 0, 0);
    }

    // ---- epilogue: logit[j] = sum_e lrelu(si+q)*wa2 + ba2 ----
    const float ba2h = ba2[head];
    float sv[4], wv[4];
    #pragma unroll
    for (int nt = 0; nt < 4; ++nt) { sv[nt] = si_s[nt * 16 + l15]; wv[nt] = wa2_s[nt * 16 + l15]; }
    #pragma unroll
    for (int mt = 0; mt < 4; ++mt) {
        #pragma unroll
        for (int reg = 0; reg < 4; ++reg) {
            float val = 0.f;
            #pragma unroll
            for (int nt = 0; nt < 4; ++nt) {
                float q = acc[mt][nt][reg] + sv[nt];
                val += lrelu(q) * wv[nt];
            }
            val += __shfl_xor(val, 1, 64);
            val += __shfl_xor(val, 2, 64);
            val += __shfl_xor(val, 4, 64);
            val += __shfl_xor(val, 8, 64);
            if (l15 == 0)
                logit_s[wid * 64 + mt * 16 + quad * 4 + reg] = val + ba2h;
        }
    }
    __syncthreads();

    // ---- mask + block softmax over 256 j ----
    float lg = logit_s[tid];
    if (adj[((size_t)(b * N_ + i)) * N_ + tid] == 0) lg = -1e9f;
    float m = lg;
    #pragma unroll
    for (int off = 32; off >= 1; off >>= 1) m = fmaxf(m, __shfl_xor(m, off, 64));
    if (lane == 0) red_s[wid] = m;
    __syncthreads();
    m = fmaxf(fmaxf(red_s[0], red_s[1]), fmaxf(red_s[2], red_s[3]));
    const float p = __expf(lg - m);
    float ssum = p;
    #pragma unroll
    for (int off = 32; off >= 1; off >>= 1) ssum += __shfl_xor(ssum, off, 64);
    logit_s[tid] = p;
    if (lane == 0) red_s[4 + wid] = ssum;
    __syncthreads();
    const float inv = 1.f / (red_s[4] + red_s[5] + red_s[6] + red_s[7]);

    // ---- hp[d] = sum_j attn_j * Wh[j][d] ----
    {
        const ushort_t* whp = &Wh_b[((size_t)(bh * N_ + wid * 64)) * HD_ + lane];
        float a0 = 0.f;
        #pragma unroll 8
        for (int jj = 0; jj < 64; ++jj)
            a0 += logit_s[wid * 64 + jj] * b2f(whp[(size_t)jj * HD_]);
        hp_s[tid] = a0 * inv;
    }
    __syncthreads();

    if (tid < 64) {
        const int d = tid;
        const float hp = hp_s[d] + hp_s[64 + d] + hp_s[128 + d] + hp_s[192 + d];
        float s1 = hp;
        #pragma unroll
        for (int off = 32; off >= 1; off >>= 1) s1 += __shfl_xor(s1, off, 64);
        const float mean = s1 * (1.f / 64.f);
        const float df = hp - mean;
        float s2 = df * df;
        #pragma unroll
        for (int off = 32; off >= 1; off >>= 1) s2 += __shfl_xor(s2, off, 64);
        const float var = s2 * (1.f / 64.f);
        const float o = df * __frsqrt_rn(var + EPS_) * ln_g[head * HD_ + d] + ln_b[head * HD_ + d];
        conc[(size_t)(b * N_ + i) * OUT_ + head * HD_ + d] = f2b(o);
    }
}

// ---------------------------------------------------------------------------
// out2: out = LN2(conc_b @ wo_t + bo + h). grid 128 (16 rows each), 4 waves:
// wave w covers cols w*64 (nt 0..3). Block owns full 256 cols -> LN in LDS.
// ---------------------------------------------------------------------------
__global__ __launch_bounds__(256) void out2_kernel(
    const float* __restrict__ h, const float* __restrict__ bo,
    const float* __restrict__ ln2_g, const float* __restrict__ ln2_b,
    const ushort_t* __restrict__ conc, const ushort_t* __restrict__ wo_t,
    float* __restrict__ out)
{
    const int rowbase = blockIdx.x * 16;
    const int tid = threadIdx.x, lane = tid & 63, wid = tid >> 6;
    const int quad = lane >> 4, l15 = lane & 15;

    __shared__ float s1a[16][4], s2a[16][4];

    floatx4 acc[4];
    #pragma unroll
    for (int nt = 0; nt < 4; ++nt) acc[nt] = (floatx4){0.f,0.f,0.f,0.f};

    #pragma unroll 2
    for (int ks = 0; ks < 8; ++ks) {
        short8 afr = *(const short8*)&conc[(size_t)(rowbase + l15) * 256 + ks * 32 + quad * 8];
        #pragma unroll
        for (int nt = 0; nt < 4; ++nt) {
            short8 bfr = *(const short8*)&wo_t[(size_t)(wid * 64 + nt * 16 + l15) * 256 + ks * 32 + quad * 8];
            acc[nt] = __builtin_amdgcn_mfma_f32_16x16x32_bf16(afr, bfr, acc[nt], 0, 0, 0);
        }
    }

    // x = acc + bo + h ; per-row partial sums over this wave's 64 cols
    float x[4][4], s1[4], s2[4];
    #pragma unroll
    for (int reg = 0; reg < 4; ++reg) { s1[reg] = 0.f; s2[reg] = 0.f; }
    #pragma unroll
    for (int nt = 0; nt < 4; ++nt) {
        const int col = wid * 64 + nt * 16 + l15;
        const float bv = bo[col];
        #pragma unroll
        for (int reg = 0; reg < 4; ++reg) {
            const int row = rowbase + quad * 4 + reg;
            float v = acc[nt][reg] + bv + h[(size_t)row * 256 + col];
            x[nt][reg] = v;
            s1[reg] += v;
            s2[reg] += v * v;
        }
    }
    #pragma unroll
    for (int reg = 0; reg < 4; ++reg) {
        #pragma unroll
        for (int off = 1; off <= 8; off <<= 1) {
            s1[reg] += __shfl_xor(s1[reg], off, 64);
            s2[reg] += __shfl_xor(s2[reg], off, 64);
        }
        if (l15 == 0) {
            s1a[quad * 4 + reg][wid] = s1[reg];
            s2a[quad * 4 + reg][wid] = s2[reg];
        }
    }
    __syncthreads();

    #pragma unroll
    for (int reg = 0; reg < 4; ++reg) {
        const int r = quad * 4 + reg;
        const float S1 = s1a[r][0] + s1a[r][1] + s1a[r][2] + s1a[r][3];
        const float S2 = s2a[r][0] + s2a[r][1] + s2a[r][2] + s2a[r][3];
        const float mean = S1 * (1.f / 256.f);
        const float var = S2 * (1.f / 256.f) - mean * mean;
        const float rs = __frsqrt_rn(var + EPS_);
        const int row = rowbase + r;
        #pragma unroll
        for (int nt = 0; nt < 4; ++nt) {
            const int col = wid * 64 + nt * 16 + l15;
            out[(size_t)row * 256 + col] =
                (x[nt][reg] - mean) * rs * ln2_g[col] + ln2_b[col];
        }
    }
}

// ---------------------------------------------------------------------------
extern "C" void kernel_launch(void* const* d_in, const int* in_sizes, int n_in,
                              void* d_out, int out_size, void* d_ws, size_t ws_size,
                              hipStream_t stream)
{
    const float* h    = (const float*)d_in[0];
    const int*   adj  = (const int*)  d_in[1];
    const float* W    = (const float*)d_in[2];
    const float* We1  = (const float*)d_in[3];
    const float* be1  = (const float*)d_in[4];
    const float* Wa1  = (const float*)d_in[5];
    const float* ba1  = (const float*)d_in[6];
    const float* wa2  = (const float*)d_in[7];
    const float* ba2  = (const float*)d_in[8];
    const float* ln_g = (const float*)d_in[9];
    const float* ln_b = (const float*)d_in[10];
    const float* Wo   = (const float*)d_in[11];
    const float* bo   = (const float*)d_in[12];
    const float* ln2g = (const float*)d_in[13];
    const float* ln2b = (const float*)d_in[14];

    float* ws = (float*)d_ws;
    ushort_t* h_b   = (ushort_t*)(ws + 3 * (size_t)S_);
    ushort_t* conc  = h_b + 524288;
    ushort_t* wfull = (ushort_t*)(ws + 4 * (size_t)S_);
    ushort_t* wo_t  = wfull + 262144;
    ushort_t* bw_b  = wo_t + 65536;
    float* out = (float*)d_out;

    conv_h_kernel   <<<512,  256, 0, stream>>>(h, h_b);
    build_w_kernel  <<<1024, 256, 0, stream>>>(W, We1, Wa1, wfull);
    build_wot_kernel<<<16,   256, 0, stream>>>(Wo, wo_t);
    bwprep_kernel   <<<H_,   256, 0, stream>>>(Wa1, bw_b);
    prep2_kernel    <<<256,  256, 0, stream>>>(h_b, wfull, be1, ba1, ws);
    attn_kernel     <<<B_ * H_ * N_, 256, 0, stream>>>(adj, wa2, ba2, ln_g, ln_b, ws);
    out2_kernel     <<<B_ * 16, 256, 0, stream>>>(h, bo, ln2g, ln2b, conc, wo_t, out);
}

// Round 6
// 222.727 us; speedup vs baseline: 4.8660x; 1.3182x over previous
//
#include <hip/hip_runtime.h>
#include <hip/hip_bf16.h>

#define B_ 8
#define N_ 256
#define IN_ 256
#define OUT_ 256
#define H_ 4
#define HD_ 64
#define ALPHA_ 0.2f
#define EPS_ 1e-5f

#define S_ (B_*H_*N_*HD_)   // 524288

// ws layout (float* base ws):
//   ei_f   f32   [ws + 0,    S_)          [B][H][N][64]  (+be1)
//   si_f   f32   [ws + S_,  2S_)          [B][H][N][64]  (+ba1)
//   ej_b   bf16  at ws+2S_   (S_ ushorts) [B][H][N][64]
//   Wh_b   bf16  ej_b+S_     (S_ ushorts)
//   h_b    bf16  at ws+3S_   (524288)
//   conc_b bf16  h_b+524288  (524288)
//   wfull  bf16  at ws+4S_   (262144)   [4 heads x {Wh|ei|ej|si}][256 f]
//   wo_t   bf16  wfull+262144 (65536)   [o][f]
//   bw_b   bf16  wo_t+65536   (32768)   [h][e][k: We|Wb]

typedef unsigned short ushort_t;
typedef __attribute__((ext_vector_type(8))) short short8;
typedef __attribute__((ext_vector_type(4))) float floatx4;

__device__ __forceinline__ float lrelu(float x) { return fmaxf(x, ALPHA_ * x); }
__device__ __forceinline__ float b2f(ushort_t u) { return __uint_as_float(((unsigned)u) << 16); }
__device__ __forceinline__ ushort_t f2b(float x) {   // RNE f32->bf16
    unsigned u = __float_as_uint(x);
    unsigned r = ((u >> 16) & 1u) + 0x7fffu;
    return (ushort_t)((u + r) >> 16);
}
__device__ __forceinline__ unsigned pk2(float x0, float x1) {  // 2xf32 -> packed bf16x2 (RNE)
    __hip_bfloat162 p = __float22bfloat162_rn(make_float2(x0, x1));
    return *(unsigned*)&p;
}

// ---------------------------------------------------------------------------
__global__ __launch_bounds__(256) void conv_h_kernel(
    const float* __restrict__ h, ushort_t* __restrict__ h_b)
{
    const int i = (blockIdx.x * 256 + threadIdx.x) * 4;
    float4 v = *(const float4*)&h[i];
    uint2 o; o.x = pk2(v.x, v.y); o.y = pk2(v.z, v.w);
    *(uint2*)&h_b[i] = o;
}

// ---------------------------------------------------------------------------
__global__ __launch_bounds__(256) void build_w_kernel(
    const float* __restrict__ W, const float* __restrict__ We1,
    const float* __restrict__ Wa1, ushort_t* __restrict__ wfull)
{
    const int hh = blockIdx.x >> 8, f = blockIdx.x & 255;
    const int c = threadIdx.x;
    __shared__ float Wlds[64];
    if (c < 64) Wlds[c] = W[(size_t)(hh * 256 + f) * 64 + c];
    __syncthreads();
    float v;
    if (c < 64)       v = Wlds[c];
    else if (c < 128) v = We1[(size_t)(hh * 512 + f) * 64 + (c - 64)];
    else if (c < 192) v = We1[(size_t)(hh * 512 + 256 + f) * 64 + (c - 128)];
    else {
        float s = 0.f;
        const float* wa = Wa1 + (size_t)hh * 192 * 64 + (c - 192);
        #pragma unroll 4
        for (int g = 0; g < 64; ++g) s += Wlds[g] * wa[(size_t)g * 64];
        v = s;
    }
    wfull[(size_t)(hh * 256 + c) * 256 + f] = f2b(v);
}

// ---------------------------------------------------------------------------
__global__ __launch_bounds__(256) void build_wot_kernel(
    const float* __restrict__ Wo, ushort_t* __restrict__ wo_t)
{
    const int to = blockIdx.x & 3, tf = blockIdx.x >> 2;
    const int r0 = threadIdx.x >> 6, cc = threadIdx.x & 63;
    __shared__ float t[64][65];
    for (int rr = r0; rr < 64; rr += 4)
        t[rr][cc] = Wo[(size_t)(tf * 64 + rr) * 256 + to * 64 + cc];
    __syncthreads();
    for (int rr = r0; rr < 64; rr += 4)
        wo_t[(size_t)(to * 64 + rr) * 256 + tf * 64 + cc] = f2b(t[cc][rr]);
}

// ---------------------------------------------------------------------------
__global__ __launch_bounds__(256) void bwprep_kernel(
    const float* __restrict__ Wa1, ushort_t* __restrict__ bw_b)
{
    const int hh = blockIdx.x;
    for (int idx = threadIdx.x; idx < 64 * 128; idx += 256) {
        const int e = idx >> 7, k = idx & 127;
        const int row = (k < 64) ? (128 + k) : k;
        bw_b[hh * 8192 + idx] = f2b(Wa1[(size_t)hh * 192 * 64 + row * 64 + e]);
    }
}

// ---------------------------------------------------------------------------
__global__ __launch_bounds__(256) void prep2_kernel(
    const ushort_t* __restrict__ h_b, const ushort_t* __restrict__ wfull,
    const float* __restrict__ be1, const float* __restrict__ ba1,
    float* __restrict__ ws)
{
    const int gm = blockIdx.x & 31, gn = blockIdx.x >> 5;
    const int tid = threadIdx.x, lane = tid & 63, wid = tid >> 6;
    const int quad = lane >> 4, l15 = lane & 15;

    float*    ei_f = ws;
    float*    si_f = ws + S_;
    ushort_t* ej_b = (ushort_t*)(ws + 2 * (size_t)S_);
    ushort_t* Wh_b = ej_b + S_;

    floatx4 acc[4][2];
    #pragma unroll
    for (int mt = 0; mt < 4; ++mt)
        #pragma unroll
        for (int nt = 0; nt < 2; ++nt) acc[mt][nt] = (floatx4){0.f,0.f,0.f,0.f};

    #pragma unroll 2
    for (int ks = 0; ks < 8; ++ks) {
        short8 afr[4], bfr[2];
        #pragma unroll
        for (int mt = 0; mt < 4; ++mt)
            afr[mt] = *(const short8*)&h_b[(size_t)(gm * 64 + mt * 16 + l15) * 256 + ks * 32 + quad * 8];
        #pragma unroll
        for (int nt = 0; nt < 2; ++nt)
            bfr[nt] = *(const short8*)&wfull[(size_t)(gn * 128 + wid * 32 + nt * 16 + l15) * 256 + ks * 32 + quad * 8];
        #pragma unroll
        for (int mt = 0; mt < 4; ++mt)
            #pragma unroll
            for (int nt = 0; nt < 2; ++nt)
                acc[mt][nt] = __builtin_amdgcn_mfma_f32_16x16x32_bf16(afr[mt], bfr[nt], acc[mt][nt], 0, 0, 0);
    }

    #pragma unroll
    for (int nt = 0; nt < 2; ++nt) {
        const int colg = gn * 128 + wid * 32 + nt * 16 + l15;
        const int head = colg >> 8, c = colg & 255, type = c >> 6, d = c & 63;
        #pragma unroll
        for (int mt = 0; mt < 4; ++mt)
            #pragma unroll
            for (int reg = 0; reg < 4; ++reg) {
                const int row = gm * 64 + mt * 16 + quad * 4 + reg;
                const int b = row >> 8, n = row & 255;
                const size_t idx = ((size_t)(b * H_ + head) * 256 + n) * 64 + d;
                const float v = acc[mt][nt][reg];
                if      (type == 0) Wh_b[idx] = f2b(v);
                else if (type == 1) ei_f[idx] = v + be1[head * 64 + d];
                else if (type == 2) ej_b[idx] = f2b(v);
                else                si_f[idx] = v + ba1[head * 64 + d];
            }
    }
}

// ---------------------------------------------------------------------------
// attn: one block per (b, head, ig) with NI=16 queries. 4 waves, wave owns
// 64 j. All i-invariant GEMM operands hoisted to registers:
//   ejr  (raw ej bf16 pairs)   8x uint4  = 32 VGPR
//   whf  (Wh A-frags)          8x short8 = 32 VGPR
//   bfr  ([We;Wb] B-frags)    16x short8 = 64 VGPR
// Per i: t = lrelu(ei_i + ej) built in regs -> K=128 MFMA GEMM -> logits
// -> masked softmax (adj bitmask in LDS) -> P(bf16). After loop: one
// M=16,K=256,N=64 MFMA GEMM for hp, then LN -> conc.
// ---------------------------------------------------------------------------
__global__ __launch_bounds__(256, 2) void attn_kernel(
    const int* __restrict__ adj, const float* __restrict__ wa2,
    const float* __restrict__ ba2, const float* __restrict__ ln_g,
    const float* __restrict__ ln_b, float* __restrict__ ws)
{
    const int blk  = blockIdx.x;
    const int ig   = blk & 15;
    const int head = (blk >> 4) & 3;
    const int b    = blk >> 6;
    const int i0   = ig * 16;
    const int tid  = threadIdx.x;
    const int lane = tid & 63;
    const int wid  = tid >> 6;
    const int quad = lane >> 4;
    const int l15  = lane & 15;
    const int bh   = b * H_ + head;

    __shared__ float    P_s[16 * 256];                  // 16384 B
    __shared__ ushort_t Pb_s[16 * 264];                 // 8448 B (pad 264)
    __shared__ float    ei_s[16 * 64];                  // 4096
    __shared__ float    si_s[16 * 64];                  // 4096
    __shared__ unsigned long long adjm_s[16 * 4];       // 512
    __shared__ float    hp_s[16 * 68];                  // 4352 (pad 68)
    __shared__ float    red_s[8];

    const float*    ei_f = ws;
    const float*    si_f = ws + S_;
    const ushort_t* ej_b = (const ushort_t*)(ws + 2 * (size_t)S_);
    const ushort_t* Wh_b = ej_b + S_;
    ushort_t*       conc = (ushort_t*)(ws + 3 * (size_t)S_) + 524288;
    const ushort_t* bw_b = (const ushort_t*)(ws + 4 * (size_t)S_) + 262144 + 65536;

    // ---- stage small LDS arrays ----
    {   // ei/si: 16 rows x 64 f -> one float4 per thread each
        const int ii = tid >> 4, c = tid & 15;
        *(float4*)&ei_s[ii * 64 + c * 4] =
            *(const float4*)&ei_f[((size_t)(bh * 256 + i0 + ii)) * 64 + c * 4];
        *(float4*)&si_s[ii * 64 + c * 4] =
            *(const float4*)&si_f[((size_t)(bh * 256 + i0 + ii)) * 64 + c * 4];
    }
    {   // adj bitmask: row r, thread tid -> j=tid; wave wid owns bits j=wid*64..
        int av[16];
        #pragma unroll
        for (int r = 0; r < 16; ++r)
            av[r] = adj[((size_t)(b * 256 + i0 + r)) * 256 + tid];
        #pragma unroll
        for (int r = 0; r < 16; ++r) {
            unsigned long long mk = __ballot(av[r] != 0);
            if (lane == 0) adjm_s[r * 4 + wid] = mk;
        }
    }

    // ---- hoist i-invariant GEMM operands into registers ----
    uint4  ejr[4][2];    // raw ej pairs, [mt][ks<2]
    short8 whf[4][2];    // Wh A-frags,   [mt][ks-2]
    short8 bfr[4][4];    // [We;Wb] B-frags, [nt][ks]
    #pragma unroll
    for (int mt = 0; mt < 4; ++mt) {
        const size_t jrow = (size_t)(bh * 256 + wid * 64 + mt * 16 + l15) * 64;
        #pragma unroll
        for (int kk = 0; kk < 2; ++kk) {
            ejr[mt][kk] = *(const uint4*)&ej_b[jrow + kk * 32 + quad * 8];
            whf[mt][kk] = *(const short8*)&Wh_b[jrow + kk * 32 + quad * 8];
        }
    }
    #pragma unroll
    for (int nt = 0; nt < 4; ++nt)
        #pragma unroll
        for (int ks = 0; ks < 4; ++ks)
            bfr[nt][ks] = *(const short8*)&bw_b[head * 8192 + (nt * 16 + l15) * 128 + ks * 32 + quad * 8];

    float wv[4];
    #pragma unroll
    for (int nt = 0; nt < 4; ++nt) wv[nt] = wa2[head * 64 + nt * 16 + l15];
    const float ba2h = ba2[head];

    __syncthreads();

    // ==== loop over the 16 queries ====
    for (int i = 0; i < 16; ++i) {
        floatx4 acc[4][4];
        #pragma unroll
        for (int mt = 0; mt < 4; ++mt)
            #pragma unroll
            for (int nt = 0; nt < 4; ++nt) acc[mt][nt] = (floatx4){0.f,0.f,0.f,0.f};

        #pragma unroll
        for (int ks = 0; ks < 4; ++ks) {
            short8 afr[4];
            if (ks < 2) {
                float ev[8];
                *(float4*)&ev[0] = *(const float4*)&ei_s[i * 64 + ks * 32 + quad * 8];
                *(float4*)&ev[4] = *(const float4*)&ei_s[i * 64 + ks * 32 + quad * 8 + 4];
                #pragma unroll
                for (int mt = 0; mt < 4; ++mt) {
                    const unsigned* rw = (const unsigned*)&ejr[mt][ks];
                    union { unsigned u[4]; short8 s; } ow;
                    #pragma unroll
                    for (int p = 0; p < 4; ++p) {
                        float x0 = __uint_as_float(rw[p] << 16)         + ev[2 * p];
                        float x1 = __uint_as_float(rw[p] & 0xffff0000u) + ev[2 * p + 1];
                        ow.u[p] = pk2(lrelu(x0), lrelu(x1));
                    }
                    afr[mt] = ow.s;
                }
            } else {
                #pragma unroll
                for (int mt = 0; mt < 4; ++mt) afr[mt] = whf[mt][ks - 2];
            }
            #pragma unroll
            for (int mt = 0; mt < 4; ++mt)
                #pragma unroll
                for (int nt = 0; nt < 4; ++nt)
                    acc[mt][nt] = __builtin_amdgcn_mfma_f32_16x16x32_bf16(
                        afr[mt], bfr[nt][ks], acc[mt][nt], 0, 0, 0);
        }

        // epilogue: logit[j] = sum_e lrelu(si+q)*wa2 + ba2
        float sv[4];
        #pragma unroll
        for (int nt = 0; nt < 4; ++nt) sv[nt] = si_s[i * 64 + nt * 16 + l15];
        #pragma unroll
        for (int mt = 0; mt < 4; ++mt) {
            #pragma unroll
            for (int reg = 0; reg < 4; ++reg) {
                float val = 0.f;
                #pragma unroll
                for (int nt = 0; nt < 4; ++nt)
                    val += lrelu(acc[mt][nt][reg] + sv[nt]) * wv[nt];
                val += __shfl_xor(val, 1, 64);
                val += __shfl_xor(val, 2, 64);
                val += __shfl_xor(val, 4, 64);
                val += __shfl_xor(val, 8, 64);
                if (l15 == 0)
                    P_s[i * 256 + wid * 64 + mt * 16 + quad * 4 + reg] = val + ba2h;
            }
        }
        __syncthreads();

        // masked softmax over row i (thread tid <-> j)
        float lg = P_s[i * 256 + tid];
        if (!((adjm_s[i * 4 + wid] >> lane) & 1ull)) lg = -1e9f;
        float m = lg;
        #pragma unroll
        for (int off = 32; off >= 1; off >>= 1) m = fmaxf(m, __shfl_xor(m, off, 64));
        if (lane == 0) red_s[wid] = m;
        __syncthreads();
        m = fmaxf(fmaxf(red_s[0], red_s[1]), fmaxf(red_s[2], red_s[3]));
        const float p = __expf(lg - m);
        float ssum = p;
        #pragma unroll
        for (int off = 32; off >= 1; off >>= 1) ssum += __shfl_xor(ssum, off, 64);
        if (lane == 0) red_s[4 + wid] = ssum;
        __syncthreads();
        const float inv = 1.f / (red_s[4] + red_s[5] + red_s[6] + red_s[7]);
        Pb_s[i * 264 + tid] = f2b(p * inv);
    }
    __syncthreads();   // Pb complete

    // ==== hp GEMM: M=16 (i), N=64 (d, wave wid -> d=wid*16+l15), K=256 (j) ====
    floatx4 hacc = (floatx4){0.f,0.f,0.f,0.f};
    #pragma unroll
    for (int s = 0; s < 8; ++s) {
        short8 af = *(const short8*)&Pb_s[l15 * 264 + s * 32 + quad * 8];
        short8 bf;
        #pragma unroll
        for (int jj = 0; jj < 8; ++jj)
            bf[jj] = (short)Wh_b[((size_t)(bh * 256) + s * 32 + quad * 8 + jj) * 64 + wid * 16 + l15];
        hacc = __builtin_amdgcn_mfma_f32_16x16x32_bf16(af, bf, hacc, 0, 0, 0);
    }
    #pragma unroll
    for (int reg = 0; reg < 4; ++reg)
        hp_s[(quad * 4 + reg) * 68 + wid * 16 + l15] = hacc[reg];
    __syncthreads();

    // ==== per-row LN over 64 d -> conc (bf16) ====
    const float gg = ln_g[head * 64 + lane];
    const float bb = ln_b[head * 64 + lane];
    #pragma unroll
    for (int pss = 0; pss < 4; ++pss) {
        const int r = pss * 4 + wid;
        const float v = hp_s[r * 68 + lane];
        float s1 = v, s2 = v * v;
        #pragma unroll
        for (int off = 32; off >= 1; off >>= 1) {
            s1 += __shfl_xor(s1, off, 64);
            s2 += __shfl_xor(s2, off, 64);
        }
        const float mean = s1 * (1.f / 64.f);
        const float var = s2 * (1.f / 64.f) - mean * mean;
        const float o = (v - mean) * __frsqrt_rn(var + EPS_) * gg + bb;
        conc[((size_t)(b * 256 + i0 + r)) * 256 + head * 64 + lane] = f2b(o);
    }
}

// ---------------------------------------------------------------------------
__global__ __launch_bounds__(256) void out2_kernel(
    const float* __restrict__ h, const float* __restrict__ bo,
    const float* __restrict__ ln2_g, const float* __restrict__ ln2_b,
    const ushort_t* __restrict__ conc, const ushort_t* __restrict__ wo_t,
    float* __restrict__ out)
{
    const int rowbase = blockIdx.x * 16;
    const int tid = threadIdx.x, lane = tid & 63, wid = tid >> 6;
    const int quad = lane >> 4, l15 = lane & 15;

    __shared__ float s1a[16][4], s2a[16][4];

    floatx4 acc[4];
    #pragma unroll
    for (int nt = 0; nt < 4; ++nt) acc[nt] = (floatx4){0.f,0.f,0.f,0.f};

    #pragma unroll 2
    for (int ks = 0; ks < 8; ++ks) {
        short8 afr = *(const short8*)&conc[(size_t)(rowbase + l15) * 256 + ks * 32 + quad * 8];
        #pragma unroll
        for (int nt = 0; nt < 4; ++nt) {
            short8 bfr = *(const short8*)&wo_t[(size_t)(wid * 64 + nt * 16 + l15) * 256 + ks * 32 + quad * 8];
            acc[nt] = __builtin_amdgcn_mfma_f32_16x16x32_bf16(afr, bfr, acc[nt], 0, 0, 0);
        }
    }

    float x[4][4], s1[4], s2[4];
    #pragma unroll
    for (int reg = 0; reg < 4; ++reg) { s1[reg] = 0.f; s2[reg] = 0.f; }
    #pragma unroll
    for (int nt = 0; nt < 4; ++nt) {
        const int col = wid * 64 + nt * 16 + l15;
        const float bv = bo[col];
        #pragma unroll
        for (int reg = 0; reg < 4; ++reg) {
            const int row = rowbase + quad * 4 + reg;
            float v = acc[nt][reg] + bv + h[(size_t)row * 256 + col];
            x[nt][reg] = v;
            s1[reg] += v;
            s2[reg] += v * v;
        }
    }
    #pragma unroll
    for (int reg = 0; reg < 4; ++reg) {
        #pragma unroll
        for (int off = 1; off <= 8; off <<= 1) {
            s1[reg] += __shfl_xor(s1[reg], off, 64);
            s2[reg] += __shfl_xor(s2[reg], off, 64);
        }
        if (l15 == 0) {
            s1a[quad * 4 + reg][wid] = s1[reg];
            s2a[quad * 4 + reg][wid] = s2[reg];
        }
    }
    __syncthreads();

    #pragma unroll
    for (int reg = 0; reg < 4; ++reg) {
        const int r = quad * 4 + reg;
        const float S1 = s1a[r][0] + s1a[r][1] + s1a[r][2] + s1a[r][3];
        const float S2 = s2a[r][0] + s2a[r][1] + s2a[r][2] + s2a[r][3];
        const float mean = S1 * (1.f / 256.f);
        const float var = S2 * (1.f / 256.f) - mean * mean;
        const float rs = __frsqrt_rn(var + EPS_);
        const int row = rowbase + r;
        #pragma unroll
        for (int nt = 0; nt < 4; ++nt) {
            const int col = wid * 64 + nt * 16 + l15;
            out[(size_t)row * 256 + col] =
                (x[nt][reg] - mean) * rs * ln2_g[col] + ln2_b[col];
        }
    }
}

// ---------------------------------------------------------------------------
extern "C" void kernel_launch(void* const* d_in, const int* in_sizes, int n_in,
                              void* d_out, int out_size, void* d_ws, size_t ws_size,
                              hipStream_t stream)
{
    const float* h    = (const float*)d_in[0];
    const int*   adj  = (const int*)  d_in[1];
    const float* W    = (const float*)d_in[2];
    const float* We1  = (const float*)d_in[3];
    const float* be1  = (const float*)d_in[4];
    const float* Wa1  = (const float*)d_in[5];
    const float* ba1  = (const float*)d_in[6];
    const float* wa2  = (const float*)d_in[7];
    const float* ba2  = (const float*)d_in[8];
    const float* ln_g = (const float*)d_in[9];
    const float* ln_b = (const float*)d_in[10];
    const float* Wo   = (const float*)d_in[11];
    const float* bo   = (const float*)d_in[12];
    const float* ln2g = (const float*)d_in[13];
    const float* ln2b = (const float*)d_in[14];

    float* ws = (float*)d_ws;
    ushort_t* h_b   = (ushort_t*)(ws + 3 * (size_t)S_);
    ushort_t* conc  = h_b + 524288;
    ushort_t* wfull = (ushort_t*)(ws + 4 * (size_t)S_);
    ushort_t* wo_t  = wfull + 262144;
    ushort_t* bw_b  = wo_t + 65536;
    float* out = (float*)d_out;

    conv_h_kernel   <<<512,  256, 0, stream>>>(h, h_b);
    build_w_kernel  <<<1024, 256, 0, stream>>>(W, We1, Wa1, wfull);
    build_wot_kernel<<<16,   256, 0, stream>>>(Wo, wo_t);
    bwprep_kernel   <<<H_,   256, 0, stream>>>(Wa1, bw_b);
    prep2_kernel    <<<256,  256, 0, stream>>>(h_b, wfull, be1, ba1, ws);
    attn_kernel     <<<512,  256, 0, stream>>>(adj, wa2, ba2, ln_g, ln_b, ws);
    out2_kernel     <<<B_ * 16, 256, 0, stream>>>(h, bo, ln2g, ln2b, conc, wo_t, out);
}

// Round 7
// 188.314 us; speedup vs baseline: 5.7552x; 1.1827x over previous
//
#include <hip/hip_runtime.h>
#include <hip/hip_bf16.h>

#define B_ 8
#define N_ 256
#define IN_ 256
#define OUT_ 256
#define H_ 4
#define HD_ 64
#define ALPHA_ 0.2f
#define EPS_ 1e-5f

#define S_ (B_*H_*N_*HD_)   // 524288

// ws layout (float* base ws):
//   ei_f   f32   [ws + 0,    S_)          [B][H][N][64]  (+be1)
//   si_f   f32   [ws + S_,  2S_)          [B][H][N][64]  (+ba1)
//   ej_b   bf16  at ws+2S_   (S_ ushorts) [B][H][N][64]
//   Wh_b   bf16  ej_b+S_     (S_ ushorts)
//   h_b    bf16  at ws+3S_   (524288)
//   conc_b bf16  h_b+524288  (524288)
//   wfull  bf16  at ws+4S_   (262144)   [4 heads x {Wh|ei|ej|si}][256 f]
//   wo_t   bf16  wfull+262144 (65536)   [o][f]
//   bw_b   bf16  wo_t+65536   (32768)   [h][e][k: We|Wb]

typedef unsigned short ushort_t;
typedef __attribute__((ext_vector_type(8))) short short8;
typedef __attribute__((ext_vector_type(4))) float floatx4;

__device__ __forceinline__ float lrelu(float x) { return fmaxf(x, ALPHA_ * x); }
__device__ __forceinline__ ushort_t f2b(float x) {   // RNE f32->bf16
    unsigned u = __float_as_uint(x);
    unsigned r = ((u >> 16) & 1u) + 0x7fffu;
    return (ushort_t)((u + r) >> 16);
}
__device__ __forceinline__ unsigned pk2(float x0, float x1) {  // 2xf32 -> packed bf16x2 (RNE)
    __hip_bfloat162 p = __float22bfloat162_rn(make_float2(x0, x1));
    return *(unsigned*)&p;
}

// ---------------------------------------------------------------------------
// setup: fused builders. blk<512: h->bf16; <1536: wfull; <1552: wo_t; else bw_b
// ---------------------------------------------------------------------------
__global__ __launch_bounds__(256) void setup_kernel(
    const float* __restrict__ h, const float* __restrict__ W,
    const float* __restrict__ We1, const float* __restrict__ Wa1,
    const float* __restrict__ Wo,
    ushort_t* __restrict__ h_b, ushort_t* __restrict__ wfull,
    ushort_t* __restrict__ wo_t, ushort_t* __restrict__ bw_b)
{
    const int blk = blockIdx.x;
    if (blk < 512) {
        const int i = (blk * 256 + threadIdx.x) * 4;
        float4 v = *(const float4*)&h[i];
        uint2 o; o.x = pk2(v.x, v.y); o.y = pk2(v.z, v.w);
        *(uint2*)&h_b[i] = o;
    } else if (blk < 1536) {
        const int bb = blk - 512;
        const int hh = bb >> 8, f = bb & 255;
        const int c = threadIdx.x;
        __shared__ float Wlds[64];
        if (c < 64) Wlds[c] = W[(size_t)(hh * 256 + f) * 64 + c];
        __syncthreads();
        float v;
        if (c < 64)       v = Wlds[c];
        else if (c < 128) v = We1[(size_t)(hh * 512 + f) * 64 + (c - 64)];
        else if (c < 192) v = We1[(size_t)(hh * 512 + 256 + f) * 64 + (c - 128)];
        else {
            float s = 0.f;
            const float* wa = Wa1 + (size_t)hh * 192 * 64 + (c - 192);
            #pragma unroll 4
            for (int g = 0; g < 64; ++g) s += Wlds[g] * wa[(size_t)g * 64];
            v = s;
        }
        wfull[(size_t)(hh * 256 + c) * 256 + f] = f2b(v);
    } else if (blk < 1552) {
        const int bb = blk - 1536;
        const int to = bb & 3, tf = bb >> 2;
        const int r0 = threadIdx.x >> 6, cc = threadIdx.x & 63;
        __shared__ float t[64][65];
        for (int rr = r0; rr < 64; rr += 4)
            t[rr][cc] = Wo[(size_t)(tf * 64 + rr) * 256 + to * 64 + cc];
        __syncthreads();
        for (int rr = r0; rr < 64; rr += 4)
            wo_t[(size_t)(to * 64 + rr) * 256 + tf * 64 + cc] = f2b(t[cc][rr]);
    } else {
        const int hh = blk - 1552;
        for (int idx = threadIdx.x; idx < 64 * 128; idx += 256) {
            const int e = idx >> 7, k = idx & 127;
            const int row = (k < 64) ? (128 + k) : k;
            bw_b[hh * 8192 + idx] = f2b(Wa1[(size_t)hh * 192 * 64 + row * 64 + e]);
        }
    }
}

// ---------------------------------------------------------------------------
__global__ __launch_bounds__(256) void prep2_kernel(
    const ushort_t* __restrict__ h_b, const ushort_t* __restrict__ wfull,
    const float* __restrict__ be1, const float* __restrict__ ba1,
    float* __restrict__ ws)
{
    const int gm = blockIdx.x & 31, gn = blockIdx.x >> 5;
    const int tid = threadIdx.x, lane = tid & 63, wid = tid >> 6;
    const int quad = lane >> 4, l15 = lane & 15;

    float*    ei_f = ws;
    float*    si_f = ws + S_;
    ushort_t* ej_b = (ushort_t*)(ws + 2 * (size_t)S_);
    ushort_t* Wh_b = ej_b + S_;

    floatx4 acc[4][2];
    #pragma unroll
    for (int mt = 0; mt < 4; ++mt)
        #pragma unroll
        for (int nt = 0; nt < 2; ++nt) acc[mt][nt] = (floatx4){0.f,0.f,0.f,0.f};

    #pragma unroll 2
    for (int ks = 0; ks < 8; ++ks) {
        short8 afr[4], bfr[2];
        #pragma unroll
        for (int mt = 0; mt < 4; ++mt)
            afr[mt] = *(const short8*)&h_b[(size_t)(gm * 64 + mt * 16 + l15) * 256 + ks * 32 + quad * 8];
        #pragma unroll
        for (int nt = 0; nt < 2; ++nt)
            bfr[nt] = *(const short8*)&wfull[(size_t)(gn * 128 + wid * 32 + nt * 16 + l15) * 256 + ks * 32 + quad * 8];
        #pragma unroll
        for (int mt = 0; mt < 4; ++mt)
            #pragma unroll
            for (int nt = 0; nt < 2; ++nt)
                acc[mt][nt] = __builtin_amdgcn_mfma_f32_16x16x32_bf16(afr[mt], bfr[nt], acc[mt][nt], 0, 0, 0);
    }

    #pragma unroll
    for (int nt = 0; nt < 2; ++nt) {
        const int colg = gn * 128 + wid * 32 + nt * 16 + l15;
        const int head = colg >> 8, c = colg & 255, type = c >> 6, d = c & 63;
        #pragma unroll
        for (int mt = 0; mt < 4; ++mt)
            #pragma unroll
            for (int reg = 0; reg < 4; ++reg) {
                const int row = gm * 64 + mt * 16 + quad * 4 + reg;
                const int b = row >> 8, n = row & 255;
                const size_t idx = ((size_t)(b * H_ + head) * 256 + n) * 64 + d;
                const float v = acc[mt][nt][reg];
                if      (type == 0) Wh_b[idx] = f2b(v);
                else if (type == 1) ei_f[idx] = v + be1[head * 64 + d];
                else if (type == 2) ej_b[idx] = f2b(v);
                else                si_f[idx] = v + ba1[head * 64 + d];
            }
    }
}

// ---------------------------------------------------------------------------
// attn: one block per (b, head, ig) with 16 queries. 4 waves, wave owns 64 j.
// sjacc = Wh@Wb hoisted out of the i-loop (i-invariant). The i-loop has NO
// barriers: per i, acc=sjacc + t@We (t built in regs from hoisted raw ej +
// ei_i), epilogue reduces to raw logits in P_s. One barrier, then wave-local
// masked softmax (wave w owns rows w,w+4,w+8,w+12). Then hp GEMM + LN.
// ---------------------------------------------------------------------------
__global__ __launch_bounds__(256, 2) void attn_kernel(
    const int* __restrict__ adj, const float* __restrict__ wa2,
    const float* __restrict__ ba2, const float* __restrict__ ln_g,
    const float* __restrict__ ln_b, float* __restrict__ ws)
{
    const int blk  = blockIdx.x;
    const int ig   = blk & 15;
    const int head = (blk >> 4) & 3;
    const int b    = blk >> 6;
    const int i0   = ig * 16;
    const int tid  = threadIdx.x;
    const int lane = tid & 63;
    const int wid  = tid >> 6;
    const int quad = lane >> 4;
    const int l15  = lane & 15;
    const int bh   = b * H_ + head;

    __shared__ float    P_s[16 * 256];                  // 16384 B
    __shared__ ushort_t Pb_s[16 * 264];                 // 8448 B (pad 264)
    __shared__ float    ei_s[16 * 64];                  // 4096
    __shared__ float    si_s[16 * 64];                  // 4096
    __shared__ unsigned long long adjm_s[16 * 4];       // 512
    __shared__ float    hp_s[16 * 68];                  // 4352 (pad 68)

    const float*    ei_f = ws;
    const float*    si_f = ws + S_;
    const ushort_t* ej_b = (const ushort_t*)(ws + 2 * (size_t)S_);
    const ushort_t* Wh_b = ej_b + S_;
    ushort_t*       conc = (ushort_t*)(ws + 3 * (size_t)S_) + 524288;
    const ushort_t* bw_b = (const ushort_t*)(ws + 4 * (size_t)S_) + 262144 + 65536;

    // ---- stage small LDS arrays ----
    {
        const int ii = tid >> 4, c = tid & 15;
        *(float4*)&ei_s[ii * 64 + c * 4] =
            *(const float4*)&ei_f[((size_t)(bh * 256 + i0 + ii)) * 64 + c * 4];
        *(float4*)&si_s[ii * 64 + c * 4] =
            *(const float4*)&si_f[((size_t)(bh * 256 + i0 + ii)) * 64 + c * 4];
    }
    {
        int av[16];
        #pragma unroll
        for (int r = 0; r < 16; ++r)
            av[r] = adj[((size_t)(b * 256 + i0 + r)) * 256 + tid];
        #pragma unroll
        for (int r = 0; r < 16; ++r) {
            unsigned long long mk = __ballot(av[r] != 0);
            if (lane == 0) adjm_s[r * 4 + wid] = mk;
        }
    }

    // ---- persistent per-wave registers ----
    uint4  ejr[4][2];     // raw ej bf16 pairs           (32 VGPR)
    short8 bfrWe[4][2];   // We B-frags (ks 0,1)         (32 VGPR)
    floatx4 sjacc[4][4];  // sj = Wh@Wb in C-layout      (64 VGPR)
    #pragma unroll
    for (int mt = 0; mt < 4; ++mt) {
        const size_t jrow = (size_t)(bh * 256 + wid * 64 + mt * 16 + l15) * 64;
        #pragma unroll
        for (int kk = 0; kk < 2; ++kk)
            ejr[mt][kk] = *(const uint4*)&ej_b[jrow + kk * 32 + quad * 8];
    }
    #pragma unroll
    for (int nt = 0; nt < 4; ++nt)
        #pragma unroll
        for (int ks = 0; ks < 2; ++ks)
            bfrWe[nt][ks] = *(const short8*)&bw_b[head * 8192 + (nt * 16 + l15) * 128 + ks * 32 + quad * 8];
    {   // sjacc = Wh @ Wb (ks 2,3), whf/Wb-frags are temporaries
        #pragma unroll
        for (int mt = 0; mt < 4; ++mt)
            #pragma unroll
            for (int nt = 0; nt < 4; ++nt) sjacc[mt][nt] = (floatx4){0.f,0.f,0.f,0.f};
        #pragma unroll
        for (int ks = 2; ks < 4; ++ks) {
            short8 whf[4], bfrWb[4];
            #pragma unroll
            for (int mt = 0; mt < 4; ++mt)
                whf[mt] = *(const short8*)&Wh_b[((size_t)(bh * 256 + wid * 64 + mt * 16 + l15)) * 64
                                                + (ks - 2) * 32 + quad * 8];
            #pragma unroll
            for (int nt = 0; nt < 4; ++nt)
                bfrWb[nt] = *(const short8*)&bw_b[head * 8192 + (nt * 16 + l15) * 128 + ks * 32 + quad * 8];
            #pragma unroll
            for (int mt = 0; mt < 4; ++mt)
                #pragma unroll
                for (int nt = 0; nt < 4; ++nt)
                    sjacc[mt][nt] = __builtin_amdgcn_mfma_f32_16x16x32_bf16(
                        whf[mt], bfrWb[nt], sjacc[mt][nt], 0, 0, 0);
        }
    }

    float wv[4];
    #pragma unroll
    for (int nt = 0; nt < 4; ++nt) wv[nt] = wa2[head * 64 + nt * 16 + l15];
    const float ba2h = ba2[head];

    __syncthreads();   // ei_s/si_s/adjm_s ready

    // ==== barrier-free loop over 16 queries ====
    for (int i = 0; i < 16; ++i) {
        floatx4 acc[4][4];
        #pragma unroll
        for (int mt = 0; mt < 4; ++mt)
            #pragma unroll
            for (int nt = 0; nt < 4; ++nt) acc[mt][nt] = sjacc[mt][nt];

        #pragma unroll
        for (int ks = 0; ks < 2; ++ks) {
            short8 afr[4];
            float ev[8];
            *(float4*)&ev[0] = *(const float4*)&ei_s[i * 64 + ks * 32 + quad * 8];
            *(float4*)&ev[4] = *(const float4*)&ei_s[i * 64 + ks * 32 + quad * 8 + 4];
            #pragma unroll
            for (int mt = 0; mt < 4; ++mt) {
                const unsigned* rw = (const unsigned*)&ejr[mt][ks];
                union { unsigned u[4]; short8 s; } ow;
                #pragma unroll
                for (int p = 0; p < 4; ++p) {
                    float x0 = __uint_as_float(rw[p] << 16)         + ev[2 * p];
                    float x1 = __uint_as_float(rw[p] & 0xffff0000u) + ev[2 * p + 1];
                    ow.u[p] = pk2(lrelu(x0), lrelu(x1));
                }
                afr[mt] = ow.s;
            }
            #pragma unroll
            for (int mt = 0; mt < 4; ++mt)
                #pragma unroll
                for (int nt = 0; nt < 4; ++nt)
                    acc[mt][nt] = __builtin_amdgcn_mfma_f32_16x16x32_bf16(
                        afr[mt], bfrWe[nt][ks], acc[mt][nt], 0, 0, 0);
        }

        // epilogue: raw logit[j] -> P_s (own j-range, no sync)
        float sv[4];
        #pragma unroll
        for (int nt = 0; nt < 4; ++nt) sv[nt] = si_s[i * 64 + nt * 16 + l15];
        #pragma unroll
        for (int mt = 0; mt < 4; ++mt) {
            #pragma unroll
            for (int reg = 0; reg < 4; ++reg) {
                float val = 0.f;
                #pragma unroll
                for (int nt = 0; nt < 4; ++nt)
                    val += lrelu(acc[mt][nt][reg] + sv[nt]) * wv[nt];
                val += __shfl_xor(val, 1, 64);
                val += __shfl_xor(val, 2, 64);
                val += __shfl_xor(val, 4, 64);
                val += __shfl_xor(val, 8, 64);
                if (l15 == 0)
                    P_s[i * 256 + wid * 64 + mt * 16 + quad * 4 + reg] = val + ba2h;
            }
        }
    }
    __syncthreads();   // all logits published

    // ==== wave-local masked softmax: wave wid owns rows wid, wid+4, +8, +12 ====
    #pragma unroll
    for (int rr = 0; rr < 4; ++rr) {
        const int r = rr * 4 + wid;
        float4 v = *(const float4*)&P_s[r * 256 + lane * 4];
        const unsigned mk = (unsigned)(adjm_s[r * 4 + quad] >> (l15 * 4)) & 0xFu;
        float v0 = (mk & 1u) ? v.x : -1e9f;
        float v1 = (mk & 2u) ? v.y : -1e9f;
        float v2 = (mk & 4u) ? v.z : -1e9f;
        float v3 = (mk & 8u) ? v.w : -1e9f;
        float m = fmaxf(fmaxf(v0, v1), fmaxf(v2, v3));
        #pragma unroll
        for (int off = 32; off >= 1; off >>= 1) m = fmaxf(m, __shfl_xor(m, off, 64));
        float p0 = __expf(v0 - m), p1 = __expf(v1 - m);
        float p2 = __expf(v2 - m), p3 = __expf(v3 - m);
        float s = (p0 + p1) + (p2 + p3);
        #pragma unroll
        for (int off = 32; off >= 1; off >>= 1) s += __shfl_xor(s, off, 64);
        const float inv = 1.f / s;
        uint2 o; o.x = pk2(p0 * inv, p1 * inv); o.y = pk2(p2 * inv, p3 * inv);
        *(uint2*)&Pb_s[r * 264 + lane * 4] = o;
    }
    __syncthreads();   // Pb complete

    // ==== hp GEMM: M=16 (i), N=64 (d = wid*16+l15), K=256 (j) ====
    floatx4 hacc = (floatx4){0.f,0.f,0.f,0.f};
    #pragma unroll
    for (int s = 0; s < 8; ++s) {
        short8 af = *(const short8*)&Pb_s[l15 * 264 + s * 32 + quad * 8];
        short8 bf;
        #pragma unroll
        for (int jj = 0; jj < 8; ++jj)
            bf[jj] = (short)Wh_b[((size_t)(bh * 256) + s * 32 + quad * 8 + jj) * 64 + wid * 16 + l15];
        hacc = __builtin_amdgcn_mfma_f32_16x16x32_bf16(af, bf, hacc, 0, 0, 0);
    }
    #pragma unroll
    for (int reg = 0; reg < 4; ++reg)
        hp_s[(quad * 4 + reg) * 68 + wid * 16 + l15] = hacc[reg];
    __syncthreads();

    // ==== per-row LN over 64 d -> conc (bf16) ====
    const float gg = ln_g[head * 64 + lane];
    const float bb = ln_b[head * 64 + lane];
    #pragma unroll
    for (int pss = 0; pss < 4; ++pss) {
        const int r = pss * 4 + wid;
        const float v = hp_s[r * 68 + lane];
        float s1 = v, s2 = v * v;
        #pragma unroll
        for (int off = 32; off >= 1; off >>= 1) {
            s1 += __shfl_xor(s1, off, 64);
            s2 += __shfl_xor(s2, off, 64);
        }
        const float mean = s1 * (1.f / 64.f);
        const float var = s2 * (1.f / 64.f) - mean * mean;
        const float o = (v - mean) * __frsqrt_rn(var + EPS_) * gg + bb;
        conc[((size_t)(b * 256 + i0 + r)) * 256 + head * 64 + lane] = f2b(o);
    }
}

// ---------------------------------------------------------------------------
__global__ __launch_bounds__(256) void out2_kernel(
    const float* __restrict__ h, const float* __restrict__ bo,
    const float* __restrict__ ln2_g, const float* __restrict__ ln2_b,
    const ushort_t* __restrict__ conc, const ushort_t* __restrict__ wo_t,
    float* __restrict__ out)
{
    const int rowbase = blockIdx.x * 16;
    const int tid = threadIdx.x, lane = tid & 63, wid = tid >> 6;
    const int quad = lane >> 4, l15 = lane & 15;

    __shared__ float s1a[16][4], s2a[16][4];

    floatx4 acc[4];
    #pragma unroll
    for (int nt = 0; nt < 4; ++nt) acc[nt] = (floatx4){0.f,0.f,0.f,0.f};

    #pragma unroll 2
    for (int ks = 0; ks < 8; ++ks) {
        short8 afr = *(const short8*)&conc[(size_t)(rowbase + l15) * 256 + ks * 32 + quad * 8];
        #pragma unroll
        for (int nt = 0; nt < 4; ++nt) {
            short8 bfr = *(const short8*)&wo_t[(size_t)(wid * 64 + nt * 16 + l15) * 256 + ks * 32 + quad * 8];
            acc[nt] = __builtin_amdgcn_mfma_f32_16x16x32_bf16(afr, bfr, acc[nt], 0, 0, 0);
        }
    }

    float x[4][4], s1[4], s2[4];
    #pragma unroll
    for (int reg = 0; reg < 4; ++reg) { s1[reg] = 0.f; s2[reg] = 0.f; }
    #pragma unroll
    for (int nt = 0; nt < 4; ++nt) {
        const int col = wid * 64 + nt * 16 + l15;
        const float bv = bo[col];
        #pragma unroll
        for (int reg = 0; reg < 4; ++reg) {
            const int row = rowbase + quad * 4 + reg;
            float v = acc[nt][reg] + bv + h[(size_t)row * 256 + col];
            x[nt][reg] = v;
            s1[reg] += v;
            s2[reg] += v * v;
        }
    }
    #pragma unroll
    for (int reg = 0; reg < 4; ++reg) {
        #pragma unroll
        for (int off = 1; off <= 8; off <<= 1) {
            s1[reg] += __shfl_xor(s1[reg], off, 64);
            s2[reg] += __shfl_xor(s2[reg], off, 64);
        }
        if (l15 == 0) {
            s1a[quad * 4 + reg][wid] = s1[reg];
            s2a[quad * 4 + reg][wid] = s2[reg];
        }
    }
    __syncthreads();

    #pragma unroll
    for (int reg = 0; reg < 4; ++reg) {
        const int r = quad * 4 + reg;
        const float S1 = s1a[r][0] + s1a[r][1] + s1a[r][2] + s1a[r][3];
        const float S2 = s2a[r][0] + s2a[r][1] + s2a[r][2] + s2a[r][3];
        const float mean = S1 * (1.f / 256.f);
        const float var = S2 * (1.f / 256.f) - mean * mean;
        const float rs = __frsqrt_rn(var + EPS_);
        const int row = rowbase + r;
        #pragma unroll
        for (int nt = 0; nt < 4; ++nt) {
            const int col = wid * 64 + nt * 16 + l15;
            out[(size_t)row * 256 + col] =
                (x[nt][reg] - mean) * rs * ln2_g[col] + ln2_b[col];
        }
    }
}

// ---------------------------------------------------------------------------
extern "C" void kernel_launch(void* const* d_in, const int* in_sizes, int n_in,
                              void* d_out, int out_size, void* d_ws, size_t ws_size,
                              hipStream_t stream)
{
    const float* h    = (const float*)d_in[0];
    const int*   adj  = (const int*)  d_in[1];
    const float* W    = (const float*)d_in[2];
    const float* We1  = (const float*)d_in[3];
    const float* be1  = (const float*)d_in[4];
    const float* Wa1  = (const float*)d_in[5];
    const float* ba1  = (const float*)d_in[6];
    const float* wa2  = (const float*)d_in[7];
    const float* ba2  = (const float*)d_in[8];
    const float* ln_g = (const float*)d_in[9];
    const float* ln_b = (const float*)d_in[10];
    const float* Wo   = (const float*)d_in[11];
    const float* bo   = (const float*)d_in[12];
    const float* ln2g = (const float*)d_in[13];
    const float* ln2b = (const float*)d_in[14];

    float* ws = (float*)d_ws;
    ushort_t* h_b   = (ushort_t*)(ws + 3 * (size_t)S_);
    ushort_t* conc  = h_b + 524288;
    ushort_t* wfull = (ushort_t*)(ws + 4 * (size_t)S_);
    ushort_t* wo_t  = wfull + 262144;
    ushort_t* bw_b  = wo_t + 65536;
    float* out = (float*)d_out;

    setup_kernel<<<1556, 256, 0, stream>>>(h, W, We1, Wa1, Wo, h_b, wfull, wo_t, bw_b);
    prep2_kernel<<<256,  256, 0, stream>>>(h_b, wfull, be1, ba1, ws);
    attn_kernel <<<512,  256, 0, stream>>>(adj, wa2, ba2, ln_g, ln_b, ws);
    out2_kernel <<<B_ * 16, 256, 0, stream>>>(h, bo, ln2g, ln2b, conc, wo_t, out);
}